// Round 1
// baseline (4133.277 us; speedup 1.0000x reference)
//
#include <hip/hip_runtime.h>
#include <hip/hip_bf16.h>
#include <stdint.h>

#define N_TOK 8192
#define DM    768
#define DS    16384
#define KTOP  32

// ---------------------------------------------------------------------------
// Encoder GEMM: pre[n][s] = sum_k x[n][k] * W_enc[s][k] + b_enc[s]
// NT layout (both row-major, K contiguous). 128x128 tile, 256 thr, 8x8 micro.
// ---------------------------------------------------------------------------
#define BM 128
#define BN 128
#define BK 8

__global__ __launch_bounds__(256, 2)
void enc_gemm(const float* __restrict__ X, const float* __restrict__ W,
              const float* __restrict__ bias, float* __restrict__ pre) {
  __shared__ float As[BK][BM];
  __shared__ float Bs[BK][BN];
  const int bn = blockIdx.x, bm = blockIdx.y;
  const int t  = threadIdx.x;
  const int tx = t & 15;        // -> 8 cols (n)
  const int ty = t >> 4;        // -> 8 rows (m)
  const int lr = t >> 1;        // staging row within tile (0..127)
  const int lc = (t & 1) * 4;   // staging k offset (0 or 4)

  const float* Xp = X + (size_t)(bm * BM + lr) * DM + lc;
  const float* Wp = W + (size_t)(bn * BN + lr) * DM + lc;

  float acc[8][8];
#pragma unroll
  for (int i = 0; i < 8; i++)
#pragma unroll
    for (int j = 0; j < 8; j++) acc[i][j] = 0.f;

  float4 av = *(const float4*)Xp;
  float4 bv = *(const float4*)Wp;

  for (int k0 = 0; k0 < DM; k0 += BK) {
    __syncthreads();
    As[lc + 0][lr] = av.x; As[lc + 1][lr] = av.y;
    As[lc + 2][lr] = av.z; As[lc + 3][lr] = av.w;
    Bs[lc + 0][lr] = bv.x; Bs[lc + 1][lr] = bv.y;
    Bs[lc + 2][lr] = bv.z; Bs[lc + 3][lr] = bv.w;
    __syncthreads();
    if (k0 + BK < DM) {                 // prefetch next staging tile
      av = *(const float4*)(Xp + k0 + BK);
      bv = *(const float4*)(Wp + k0 + BK);
    }
#pragma unroll
    for (int kk = 0; kk < BK; kk++) {
      float a[8], b[8];
      *(float4*)&a[0] = *(const float4*)&As[kk][ty * 8];
      *(float4*)&a[4] = *(const float4*)&As[kk][ty * 8 + 4];
      *(float4*)&b[0] = *(const float4*)&Bs[kk][tx * 8];
      *(float4*)&b[4] = *(const float4*)&Bs[kk][tx * 8 + 4];
#pragma unroll
      for (int i = 0; i < 8; i++)
#pragma unroll
        for (int j = 0; j < 8; j++)
          acc[i][j] += a[i] * b[j];
    }
  }

  const int row0 = bm * BM + ty * 8;
  const int col0 = bn * BN + tx * 8;
  float bvals[8];
  *(float4*)&bvals[0] = *(const float4*)&bias[col0];
  *(float4*)&bvals[4] = *(const float4*)&bias[col0 + 4];
#pragma unroll
  for (int i = 0; i < 8; i++) {
    float4 o0, o1;
    o0.x = acc[i][0] + bvals[0]; o0.y = acc[i][1] + bvals[1];
    o0.z = acc[i][2] + bvals[2]; o0.w = acc[i][3] + bvals[3];
    o1.x = acc[i][4] + bvals[4]; o1.y = acc[i][5] + bvals[5];
    o1.z = acc[i][6] + bvals[6]; o1.w = acc[i][7] + bvals[7];
    float* prow = pre + (size_t)(row0 + i) * DS + col0;
    *(float4*)&prow[0] = o0;
    *(float4*)&prow[4] = o1;
  }
}

// ---------------------------------------------------------------------------
// Row-wise exact top-32 via MSB-first 8-bit radix select.
// One block (256 thr) per row; 64 values/thread in registers (cyclic layout).
// Ties at the threshold broken by LOWEST index (lax.top_k stability).
// Writes the full zeroed+scattered latents row and a compact (idx,val) list.
// ---------------------------------------------------------------------------
__device__ __forceinline__ unsigned f2key(float f) {
  unsigned u = __float_as_uint(f);
  return (u & 0x80000000u) ? ~u : (u | 0x80000000u);   // ascending key order
}

__global__ __launch_bounds__(256)
void topk_kernel(const float* __restrict__ pre, float* __restrict__ latents,
                 int* __restrict__ tk_idx, float* __restrict__ tk_val) {
  const int row = blockIdx.x;
  const int t   = threadIdx.x;
  const int w   = t >> 6;                 // wave id (4 waves)
  const float* p = pre + (size_t)row * DS;

  float v[64];
#pragma unroll
  for (int j = 0; j < 64; j++) v[j] = p[t + j * 256];

  __shared__ int hist[4][256];
  __shared__ int sh_digit, sh_rank;
  __shared__ int eq_n, out_cnt;
  __shared__ int eq_idx[256];

  unsigned prefix = 0, mask = 0;
  int rank = KTOP;                        // how many still needed from matching set
  for (int pass = 0; pass < 4; pass++) {
    const int shift = 24 - 8 * pass;
#pragma unroll
    for (int q = 0; q < 4; q++) hist[q][t] = 0;
    __syncthreads();
#pragma unroll
    for (int j = 0; j < 64; j++) {
      unsigned key = f2key(v[j]);
      if ((key & mask) == prefix)
        atomicAdd(&hist[w][(key >> shift) & 255], 1);
    }
    __syncthreads();
    if (t == 0) {
      int r = rank, digit = 0;
      for (int b = 255; b >= 0; b--) {
        int c = hist[0][b] + hist[1][b] + hist[2][b] + hist[3][b];
        if (c >= r) { digit = b; break; }
        r -= c;
      }
      sh_digit = digit; sh_rank = r;
    }
    __syncthreads();
    prefix |= ((unsigned)sh_digit) << shift;
    mask   |= (0xFFu << shift);
    rank    = sh_rank;
  }
  const unsigned T = prefix;              // exact key of the 32nd-largest value

  if (t == 0) { eq_n = 0; out_cnt = 0; }
  __syncthreads();

  float* lrow = latents + (size_t)row * DS;
#pragma unroll
  for (int j = 0; j < 64; j++) {
    const int i = t + j * 256;
    const unsigned key = f2key(v[j]);
    float outv = 0.f;
    if (key > T) {
      outv = v[j];
      int slot = atomicAdd(&out_cnt, 1);
      tk_idx[row * KTOP + slot] = i;
      tk_val[row * KTOP + slot] = v[j];
    } else if (key == T) {
      int e = atomicAdd(&eq_n, 1);
      if (e < 256) eq_idx[e] = i;
    }
    lrow[i] = outv;                        // coalesced zero-or-value write
  }
  __syncthreads();

  if (t == 0) {
    const int need = rank;                 // equals to include (>=1)
    const int en   = eq_n > 256 ? 256 : eq_n;
    unsigned u = (T & 0x80000000u) ? (T & 0x7FFFFFFFu) : ~T;
    const float tval = __uint_as_float(u);
    int last = -1;
    for (int c = 0; c < need; c++) {       // pick `need` smallest indices
      int best = 0x7FFFFFFF;
      for (int e = 0; e < en; e++) {
        int ie = eq_idx[e];
        if (ie > last && ie < best) best = ie;
      }
      if (best == 0x7FFFFFFF) break;       // pathological overflow guard
      last = best;
      lrow[best] = tval;
      tk_idx[row * KTOP + out_cnt + c] = best;
      tk_val[row * KTOP + out_cnt + c] = tval;
    }
  }
}

// ---------------------------------------------------------------------------
// W_dec [DM][DS] -> WdT [DS][DM]  (makes decoder feature-gathers contiguous)
// ---------------------------------------------------------------------------
__global__ __launch_bounds__(256)
void wdec_transpose(const float* __restrict__ Wd, float* __restrict__ WdT) {
  __shared__ float tile[32][33];
  const int bs = blockIdx.x * 32;   // DS offset
  const int bd = blockIdx.y * 32;   // DM offset
  const int tx = threadIdx.x & 31, ty = threadIdx.x >> 5;  // 32 x 8
#pragma unroll
  for (int i = 0; i < 32; i += 8)
    tile[ty + i][tx] = Wd[(size_t)(bd + ty + i) * DS + bs + tx];
  __syncthreads();
#pragma unroll
  for (int i = 0; i < 32; i += 8)
    WdT[(size_t)(bs + ty + i) * DM + bd + tx] = tile[tx][ty + i];
}

// ---------------------------------------------------------------------------
// Decoder: recon[n][:] = sum_j val_j * WdT[idx_j][:]   (32 nnz per row)
// ---------------------------------------------------------------------------
__global__ __launch_bounds__(256)
void decoder_kernel(const float* __restrict__ WdT, const int* __restrict__ tk_idx,
                    const float* __restrict__ tk_val, float* __restrict__ recon) {
  const int row = blockIdx.x;
  const int t   = threadIdx.x;
  __shared__ int   sidx[KTOP];
  __shared__ float sval[KTOP];
  if (t < KTOP) {
    sidx[t] = tk_idx[row * KTOP + t];
    sval[t] = tk_val[row * KTOP + t];
  }
  __syncthreads();
  float a0 = 0.f, a1 = 0.f, a2 = 0.f;
#pragma unroll 4
  for (int j = 0; j < KTOP; j++) {
    const float* wr = WdT + (size_t)sidx[j] * DM;
    const float s = sval[j];
    a0 += s * wr[t];
    a1 += s * wr[t + 256];
    a2 += s * wr[t + 512];
  }
  float* r = recon + (size_t)row * DM;
  r[t] = a0; r[t + 256] = a1; r[t + 512] = a2;
}

// ---------------------------------------------------------------------------
extern "C" void kernel_launch(void* const* d_in, const int* in_sizes, int n_in,
                              void* d_out, int out_size, void* d_ws, size_t ws_size,
                              hipStream_t stream) {
  (void)in_sizes; (void)n_in; (void)out_size; (void)ws_size;
  const float* x     = (const float*)d_in[0];
  const float* W_enc = (const float*)d_in[1];
  const float* b_enc = (const float*)d_in[2];
  const float* W_dec = (const float*)d_in[3];
  // d_in[4] is k (==32), fixed by the problem; KTOP is compile-time.

  float* out     = (float*)d_out;
  float* recon   = out;                                   // [N_TOK * DM]
  float* latents = out + (size_t)N_TOK * DM;              // [N_TOK * DS]
  float* pre     = latents + (size_t)N_TOK * DS;          // [N_TOK * DS]

  float* WdT   = (float*)d_ws;                            // DS*DM floats (50.3 MB)
  int*   tkidx = (int*)(WdT + (size_t)DS * DM);           // N_TOK*KTOP ints
  float* tkval = (float*)(tkidx + (size_t)N_TOK * KTOP);  // N_TOK*KTOP floats

  hipLaunchKernelGGL(wdec_transpose, dim3(DS / 32, DM / 32), dim3(256), 0, stream,
                     W_dec, WdT);
  hipLaunchKernelGGL(enc_gemm, dim3(DS / BN, N_TOK / BM), dim3(256), 0, stream,
                     x, W_enc, b_enc, pre);
  hipLaunchKernelGGL(topk_kernel, dim3(N_TOK), dim3(256), 0, stream,
                     pre, latents, tkidx, tkval);
  hipLaunchKernelGGL(decoder_kernel, dim3(N_TOK), dim3(256), 0, stream,
                     WdT, tkidx, tkval, recon);
}